// Round 2
// baseline (220.437 us; speedup 1.0000x reference)
//
#include <hip/hip_runtime.h>

// SoftEmbeddedDecisionRules: balanced binary hierarchy over C=1024 classes.
// out[b,c] = prod over 10 levels of the 2-way softmax prob of c's branch;
// 2-way softmax == sigmoid(diff of child means). Levels 9,8 in registers,
// levels 7..2 via a 6-step __shfl_xor butterfly within each wave (each wave
// owns a contiguous 256-class quarter), levels 1,0 from 4 quarter sums via
// 16 B of LDS + ONE barrier. No LDS tree, no barrier chain.

#define C 1024

__device__ __forceinline__ float sigd(float d) {  // 1/(1+exp(d))
    return 1.0f / (1.0f + __expf(d));
}

__global__ __launch_bounds__(256) void hier_softmax_kernel(
    const float* __restrict__ in, float* __restrict__ out) {
    __shared__ float qsum[4];
    const int row = blockIdx.x;
    const int tid = threadIdx.x;
    const int wave = tid >> 6;

    const float4 v = ((const float4*)(in + (size_t)row * C))[tid];

    // level 9 (children seg=1): pairs inside this thread's float4
    const float pA = sigd(v.y - v.x);   // p(left) of pair (x,y)
    const float pB = sigd(v.w - v.z);
    const float s2a = v.x + v.y, s2b = v.z + v.w;
    // level 8 (children seg=2): this thread's quad node
    const float p8 = sigd((s2b - s2a) * 0.5f);

    float S = s2a + s2b;  // this thread's seg-4 block sum
    float common = 1.0f;  // running product of branch probs, levels 7..2
    float inv = 0.25f;    // 1/seg of children at current level
#pragma unroll
    for (int m = 1; m <= 32; m <<= 1) {
        const float sib = __shfl_xor(S, m, 64);
        common *= sigd((sib - S) * inv);  // p(own branch) = sigmoid((S-sib)/seg)
        S += sib;                         // merge to parent block
        inv *= 0.5f;
    }
    // S = this wave's quarter sum (seg 256), identical across the wave
    if ((tid & 63) == 0) qsum[wave] = S;
    __syncthreads();
    const float q0 = qsum[0], q1 = qsum[1], q2 = qsum[2], q3 = qsum[3];
    const float topL = sigd(((q2 + q3) - (q0 + q1)) * (1.0f / 512.0f));  // level 0: p(left half)
    const float pq01 = sigd((q1 - q0) * (1.0f / 256.0f));                // level 1: p(q0|left)
    const float pq23 = sigd((q3 - q2) * (1.0f / 256.0f));                // level 1: p(q2|right)

    const float pl0 = (wave < 2) ? topL : (1.0f - topL);
    const float pqh = (wave < 2) ? pq01 : pq23;
    const float pl1 = (wave & 1) ? (1.0f - pqh) : pqh;
    common *= pl0 * pl1;

    const float cl = common * p8;
    const float cr = common * (1.0f - p8);
    float4 o;
    o.x = cl * pA;
    o.y = cl * (1.0f - pA);
    o.z = cr * pB;
    o.w = cr * (1.0f - pB);
    ((float4*)(out + (size_t)row * C))[tid] = o;
}

extern "C" void kernel_launch(void* const* d_in, const int* in_sizes, int n_in,
                              void* d_out, int out_size, void* d_ws, size_t ws_size,
                              hipStream_t stream) {
    const float* in = (const float*)d_in[0];
    float* out = (float*)d_out;
    const int B = in_sizes[0] / C;  // 32768
    hier_softmax_kernel<<<B, 256, 0, stream>>>(in, out);
}